// Round 6
// baseline (400.181 us; speedup 1.0000x reference)
//
#include <hip/hip_runtime.h>
#include <math.h>

// Problem constants (fixed-shape problem)
#define NN 131072   // nodes
#define G  256      // groups
#define E  384      // embed
#define H  6        // heads
#define DH 64       // head dim
#define OUTD 256    // output dim
#define MAXN 1024   // max segment length

#define CHK 128     // nodes per fused chunk
#define SLOTS 8     // max chunks per group
#define TILE 32     // nodes per LDS tile
#define PART_STRIDE 2316   // 6*384 acc + 6 m + 6 l

// Workspace layout (float indices)
#define WS_QK   0                       // 6*384 folded q@Wk
#define WS_C    2304                    // 6 folded q@bk
#define WS_OFF  2432                    // 256 int32 segment offsets
#define WS_QV   2944                    // 384 projected+scaled query
#define WS_WL   3328                    // 2048 int32 worklist (g<<3|s)
#define WS_M    5376                    // 1 int32 worklist count
#define WS_CS   5632                    // 256 int32 exclusive chunk-count scan
#define WS_PART 6144                    // 2048 slots x 2316 partials
#define WS_WVT  (WS_PART + G*SLOTS*PART_STRIDE)  // 384x384 Wv^T [e][i]
#define WS_WOT  (WS_WVT + E*E)          // 384x384 Wo^T [e][i]
#define WS_WPT  (WS_WOT + E*E)          // 384x256 Wp^T [e][o]

// async global->LDS, 16B per lane; lds dest = wave-uniform base + lane*16
__device__ __forceinline__ void gload16(const float* g, float* l) {
  __builtin_amdgcn_global_load_lds(
      (const __attribute__((address_space(1))) unsigned int*)g,
      (__attribute__((address_space(3))) unsigned int*)l, 16, 0, 0);
}

// ---------------------------------------------------------------------------
// K0a: block 0: offset scan + chunk-count scan + compacted worklist.
// blocks 1..96: qv rows.  qv = 0.125*(query@Wq.T + bq)
// ---------------------------------------------------------------------------
__global__ __launch_bounds__(256) void k0a_scan_qv(
    const int* __restrict__ sizes, const float* __restrict__ query,
    const float* __restrict__ Wq, const float* __restrict__ bq,
    float* __restrict__ wsf) {
  const int tid = threadIdx.x;
  if (blockIdx.x == 0) {
    __shared__ int s_scan[G];
    __shared__ int s_scan2[G];
    const int sz = sizes[tid];
    s_scan[tid] = sz;
    const int nch = (sz + CHK - 1) >> 7;           // 1..8
    s_scan2[tid] = nch;
    __syncthreads();
    for (int d = 1; d < G; d <<= 1) {
      int t = (tid >= d) ? s_scan[tid - d] : 0;
      int t2 = (tid >= d) ? s_scan2[tid - d] : 0;
      __syncthreads();
      s_scan[tid] += t;
      s_scan2[tid] += t2;
      __syncthreads();
    }
    ((int*)(wsf + WS_OFF))[tid] = s_scan[tid] - sz;    // exclusive node offset
    const int pos = s_scan2[tid] - nch;
    ((int*)(wsf + WS_CS))[tid] = pos;                  // exclusive chunk scan
    int* wl = (int*)(wsf + WS_WL);
    for (int s = 0; s < nch; s++) wl[pos + s] = (tid << 3) | s;
    if (tid == G - 1) ((int*)(wsf + WS_M))[0] = s_scan2[G - 1];
  } else {
    const int lane = tid & 63;
    const int i = (blockIdx.x - 1) * 4 + (tid >> 6);   // 0..383
    float a = 0.f;
#pragma unroll
    for (int j = 0; j < 6; j++)
      a += Wq[(size_t)i * E + j * 64 + lane] * query[j * 64 + lane];
#pragma unroll
    for (int mm = 1; mm < 64; mm <<= 1) a += __shfl_xor(a, mm, 64);
    if (lane == 0) wsf[WS_QV + i] = 0.125f * (a + bq[i]);
  }
}

// ---------------------------------------------------------------------------
// K0b: qk[h][e] = sum_d qv[h*64+d]*Wk[h*64+d][e].  36 blocks = (h, e-chunk64).
// ---------------------------------------------------------------------------
__global__ __launch_bounds__(256) void k0b_qk(
    const float* __restrict__ Wk, const float* __restrict__ bk,
    float* __restrict__ wsf) {
  __shared__ float qv_s[64];
  __shared__ float ps[256];
  const int h = blockIdx.x / 6, ec = blockIdx.x % 6;
  const int tid = threadIdx.x;
  if (tid < 64) qv_s[tid] = wsf[WS_QV + h * 64 + tid];
  __syncthreads();
  const int el = tid & 63, dq = tid >> 6;
  float a = 0.f;
#pragma unroll 4
  for (int d = dq * 16; d < dq * 16 + 16; d++)
    a += qv_s[d] * Wk[(size_t)(h * 64 + d) * E + ec * 64 + el];
  ps[tid] = a;
  __syncthreads();
  if (tid < 64)
    wsf[WS_QK + h * E + ec * 64 + tid] =
        ps[tid] + ps[64 + tid] + ps[128 + tid] + ps[192 + tid];
  if (ec == 0 && tid < 64) {                       // wave 0: c[h]
    float p = qv_s[tid] * bk[h * 64 + tid];
#pragma unroll
    for (int mm = 1; mm < 64; mm <<= 1) p += __shfl_xor(p, mm, 64);
    if (tid == 0) wsf[WS_C + h] = p;
  }
}

// ---------------------------------------------------------------------------
// K0t: transpose Wv, Wo (384x384) and Wp (256x384) into ws, 64x64 LDS tiles.
// ---------------------------------------------------------------------------
__global__ __launch_bounds__(256) void k0t_transpose(
    const float* __restrict__ Wv, const float* __restrict__ Wo,
    const float* __restrict__ Wp, float* __restrict__ wsf) {
  __shared__ float s[64][65];
  const int b = blockIdx.x;
  const float* src;
  float* dst;
  int R, tr, tc;
  if (b < 36)      { src = Wv; dst = wsf + WS_WVT; R = 384; tr = b / 6;        tc = b % 6; }
  else if (b < 72) { src = Wo; dst = wsf + WS_WOT; R = 384; tr = (b - 36) / 6; tc = (b - 36) % 6; }
  else             { src = Wp; dst = wsf + WS_WPT; R = 256; tr = (b - 72) / 6; tc = (b - 72) % 6; }
  const int r0 = tr * 64, c0 = tc * 64;
#pragma unroll
  for (int k = 0; k < 16; k++) {
    int idx = k * 256 + threadIdx.x;
    int r = idx >> 6, cc = idx & 63;
    s[r][cc] = src[(size_t)(r0 + r) * E + c0 + cc];
  }
  __syncthreads();
#pragma unroll
  for (int k = 0; k < 16; k++) {
    int idx = k * 256 + threadIdx.x;
    int cc = idx >> 6, r = idx & 63;
    dst[(size_t)(c0 + cc) * R + r0 + r] = s[r][cc];
  }
}

// ---------------------------------------------------------------------------
// K12 v3: online-flash over 32-node LDS tiles staged with global_load_lds
// (MLP decoupled from VGPRs: whole 48KB tile in flight).  384 thr / 6 waves.
// Per tile: stage -> scores (waves 0-1, k1 8-lane layout) -> per-head online
// softmax (wave h = head h) -> rescale+accumulate acc[6][4] (thread = f4col
// x node-quarter, conflict-free b128).  x read ONCE, never through VGPRs.
// ---------------------------------------------------------------------------
__global__ __launch_bounds__(384, 3) void k12_fused(
    const float* __restrict__ x, const int* __restrict__ sizes,
    float* __restrict__ wsf) {
  __shared__ float xt[TILE * 384];     // 48 KB tile (flat: global_load_lds)
  __shared__ float qk_l[8 * 292];      // 9.3 KB
  __shared__ float pe[TILE * 8];       // scores -> exp'd probs, [n][8]
  __shared__ float c_s[8];
  __shared__ float s_m[8], s_l[8], s_alpha[8];
  const int M = ((const int*)(wsf + WS_M))[0];
  if ((int)blockIdx.x >= M) return;
  const int item = ((const int*)(wsf + WS_WL))[blockIdx.x];
  const int g = item >> 3, s = item & 7;
  const int Ng = sizes[g];
  const int rem = Ng - s * CHK;
  const int clen = rem < CHK ? rem : CHK;
  const int n0 = ((const int*)(wsf + WS_OFF))[g] + s * CHK;
  const int nt = (clen + TILE - 1) >> 5;           // 1..4 real tiles
  const int tid = threadIdx.x;
  const int lane = tid & 63, w = tid >> 6;         // 6 waves

  for (int idx = tid; idx < 2304; idx += 384) {    // qk: k1-proven layout
    int sub = idx / 288, r3 = idx % 288;
    int h = r3 / 48, r2 = r3 % 48, j = r2 >> 2, r = r2 & 3;
    qk_l[sub * 292 + h * 48 + j * 4 + r] =
        wsf[WS_QK + h * E + (j * 8 + sub) * 4 + r];
  }
  if (tid < 8) {
    c_s[tid] = (tid < 6) ? wsf[WS_C + tid] : 0.f;
    s_m[tid] = -3.0e38f;
    s_l[tid] = 0.f;
  }

  const int f4 = tid % 96, np = tid / 96;          // acc-phase identity
  float acc[6][4];
#pragma unroll
  for (int h = 0; h < 6; h++)
#pragma unroll
    for (int c = 0; c < 4; c++) acc[h][c] = 0.f;

  const size_t xcap = (size_t)NN * E - 4;          // 16B-aligned clamp
  const int sub = lane & 7, nod = lane >> 3;

  for (int t = 0; t < nt; t++) {
    {  // stage tile t: up to 48 segments of 1KB; wave w takes segs w,w+6,...
      const size_t tb = (size_t)(n0 + t * TILE) * E;
      int nbytes = (clen - t * TILE) * (E * 4);
      if (nbytes > TILE * E * 4) nbytes = TILE * E * 4;
      const int nseg = (nbytes + 1023) >> 10;
#pragma unroll
      for (int it = 0; it < 8; it++) {
        const int seg = it * 6 + w;
        if (seg < nseg) {
          size_t gi = tb + seg * 256 + lane * 4;
          if (gi > xcap) gi = xcap;
          gload16(x + gi, &xt[seg * 256 + lane * 4]);
        }
      }
    }
    __syncthreads();                               // drains DMA (vmcnt 0)

    if (w < 2) {  // scores: wave w -> 16 nodes {w*16+nod, w*16+8+nod}
      float a2[2][6];
#pragma unroll
      for (int o = 0; o < 2; o++)
#pragma unroll
        for (int h = 0; h < 6; h++) a2[o][h] = 0.f;
#pragma unroll 4
      for (int j = 0; j < 12; j++) {
        float4 qk4[6];
#pragma unroll
        for (int h = 0; h < 6; h++)
          qk4[h] = *(const float4*)&qk_l[sub * 292 + h * 48 + j * 4];
        float4 xv[2];
#pragma unroll
        for (int o = 0; o < 2; o++)
          xv[o] = *(const float4*)&xt[(w * 16 + o * 8 + nod) * 384 +
                                      (j * 8 + sub) * 4];
#pragma unroll
        for (int o = 0; o < 2; o++)
#pragma unroll
          for (int h = 0; h < 6; h++)
            a2[o][h] += qk4[h].x * xv[o].x + qk4[h].y * xv[o].y
                      + qk4[h].z * xv[o].z + qk4[h].w * xv[o].w;
      }
#pragma unroll
      for (int o = 0; o < 2; o++) {
#pragma unroll
        for (int h = 0; h < 6; h++) {
          a2[o][h] += __shfl_xor(a2[o][h], 1, 64);
          a2[o][h] += __shfl_xor(a2[o][h], 2, 64);
          a2[o][h] += __shfl_xor(a2[o][h], 4, 64);
        }
        float v = a2[o][0];
#pragma unroll
        for (int h = 1; h < 6; h++) v = (sub == h) ? a2[o][h] : v;
        const int nl = w * 16 + o * 8 + nod;       // node local to tile
        if (sub < 6)
          pe[nl * 8 + sub] =
              (t * TILE + nl < clen) ? v + c_s[sub] : -1.0e30f;
      }
    }
    __syncthreads();

    {  // online-softmax stats: wave w owns head w (6 waves, 6 heads)
      const int n = lane & 31;
      const float v = pe[n * 8 + w];
      float mt = v;
#pragma unroll
      for (int mm = 1; mm < 64; mm <<= 1) mt = fmaxf(mt, __shfl_xor(mt, mm, 64));
      const float mold = s_m[w];
      const float mnew = fmaxf(mold, mt);
      const float e = __expf(v - mnew);
      float lt = (lane < 32) ? e : 0.f;
#pragma unroll
      for (int mm = 1; mm < 64; mm <<= 1) lt += __shfl_xor(lt, mm, 64);
      if (lane < 32) pe[n * 8 + w] = e;
      if (lane == 0) {
        const float alpha = __expf(mold - mnew);
        s_alpha[w] = alpha;
        s_l[w] = s_l[w] * alpha + lt;
        s_m[w] = mnew;
      }
    }
    __syncthreads();

    {  // accumulate: thread (f4col, np): 8 nodes, b128 conflict-free
      float al[6];
#pragma unroll
      for (int h = 0; h < 6; h++) al[h] = s_alpha[h];
#pragma unroll
      for (int h = 0; h < 6; h++)
#pragma unroll
        for (int c = 0; c < 4; c++) acc[h][c] *= al[h];
#pragma unroll
      for (int n8 = 0; n8 < 8; n8++) {
        const int n = np * 8 + n8;
        const float4 xv = *(const float4*)&xt[n * 384 + f4 * 4];
        const float4 pA = *(const float4*)&pe[n * 8];
        const float2 pB = *(const float2*)&pe[n * 8 + 4];
        acc[0][0] += pA.x * xv.x; acc[0][1] += pA.x * xv.y;
        acc[0][2] += pA.x * xv.z; acc[0][3] += pA.x * xv.w;
        acc[1][0] += pA.y * xv.x; acc[1][1] += pA.y * xv.y;
        acc[1][2] += pA.y * xv.z; acc[1][3] += pA.y * xv.w;
        acc[2][0] += pA.z * xv.x; acc[2][1] += pA.z * xv.y;
        acc[2][2] += pA.z * xv.z; acc[2][3] += pA.z * xv.w;
        acc[3][0] += pA.w * xv.x; acc[3][1] += pA.w * xv.y;
        acc[3][2] += pA.w * xv.z; acc[3][3] += pA.w * xv.w;
        acc[4][0] += pB.x * xv.x; acc[4][1] += pB.x * xv.y;
        acc[4][2] += pB.x * xv.z; acc[4][3] += pB.x * xv.w;
        acc[5][0] += pB.y * xv.x; acc[5][1] += pB.y * xv.y;
        acc[5][2] += pB.y * xv.z; acc[5][3] += pB.y * xv.w;
      }
    }
    __syncthreads();                               // acc reads done -> restage
  }

  // epilogue: np-combine through dead xt buffer, write partial slot
#pragma unroll
  for (int h = 0; h < 6; h++)
    *(float4*)&xt[(np * 6 + h) * 384 + f4 * 4] =
        make_float4(acc[h][0], acc[h][1], acc[h][2], acc[h][3]);
  __syncthreads();
  float* pslot = wsf + WS_PART + (size_t)blockIdx.x * PART_STRIDE;
#pragma unroll
  for (int h = 0; h < 6; h++) {
    float a = xt[(0 * 6 + h) * 384 + tid] + xt[(1 * 6 + h) * 384 + tid]
            + xt[(2 * 6 + h) * 384 + tid] + xt[(3 * 6 + h) * 384 + tid];
    pslot[h * E + tid] = a;
  }
  if (tid < 6) {
    pslot[2304 + tid] = s_m[tid];
    pslot[2310 + tid] = s_l[tid];
  }
}

// ---------------------------------------------------------------------------
// K3: one block (768 thr) per group.  Flash-combine <=8 chunk partials
// (base from precomputed chunk scan) -> xb; then thread-per-output chain on
// transposed weights (coalesced, L2-resident), K-split, combine via LDS.
// ---------------------------------------------------------------------------
__global__ __launch_bounds__(768) void k3_group(
    const float* __restrict__ wsf, const int* __restrict__ sizes,
    const float* __restrict__ bv, const float* __restrict__ bo,
    const float* __restrict__ bp, float* __restrict__ out) {
  __shared__ float xb[H * E];          // 9.2 KB
  __shared__ float pooled[E];
  __shared__ float om[E];
  __shared__ float ps[768];
  __shared__ float wgt[SLOTS][H];
  __shared__ float linv[H];
  const int tid = threadIdx.x;
  const int g = blockIdx.x;
  const int nch = (sizes[g] + CHK - 1) >> 7;       // 1..8
  const int base_s = ((const int*)(wsf + WS_CS))[g];
  const float* pg = wsf + WS_PART + (size_t)base_s * PART_STRIDE;
  const float* wvt = wsf + WS_WVT;
  const float* wot = wsf + WS_WOT;
  const float* wpt = wsf + WS_WPT;

  if (tid < H) {
    float m = -3.0e38f;
    for (int s = 0; s < nch; s++)
      m = fmaxf(m, pg[(size_t)s * PART_STRIDE + 2304 + tid]);
    float L = 0.f;
    for (int s = 0; s < nch; s++) {
      float wv_ = __expf(pg[(size_t)s * PART_STRIDE + 2304 + tid] - m);
      wgt[s][tid] = wv_;
      L += pg[(size_t)s * PART_STRIDE + 2310 + tid] * wv_;
    }
    linv[tid] = 1.f / L;
  }
  __syncthreads();
  for (int idx = tid; idx < H * E; idx += 768) {
    int h = idx / E;
    float a = 0.f;
    for (int s = 0; s < nch; s++) a += pg[(size_t)s * PART_STRIDE + idx] * wgt[s][h];
    xb[idx] = a * linv[h];
  }
  __syncthreads();

  {  // stage 1: pooled[i] = Wv[i,:]·xb[head(i),:] + bv
    const int i = tid % 384, ks = tid / 384;
    const float* xh = xb + (i >> 6) * E + ks * 192;
    const float* wp_ = wvt + (size_t)(ks * 192) * E + i;
    float a0 = 0.f, a1 = 0.f, a2 = 0.f, a3 = 0.f;
#pragma unroll 4
    for (int e = 0; e < 192; e += 4) {
      a0 += wp_[(size_t)(e + 0) * E] * xh[e + 0];
      a1 += wp_[(size_t)(e + 1) * E] * xh[e + 1];
      a2 += wp_[(size_t)(e + 2) * E] * xh[e + 2];
      a3 += wp_[(size_t)(e + 3) * E] * xh[e + 3];
    }
    ps[tid] = (a0 + a1) + (a2 + a3);
  }
  __syncthreads();
  if (tid < 384) pooled[tid] = ps[tid] + ps[384 + tid] + bv[tid];
  __syncthreads();

  {  // stage 2: om[i] = Wo[i,:]·pooled + bo
    const int i = tid % 384, ks = tid / 384;
    const float* xh = pooled + ks * 192;
    const float* wp_ = wot + (size_t)(ks * 192) * E + i;
    float a0 = 0.f, a1 = 0.f, a2 = 0.f, a3 = 0.f;
#pragma unroll 4
    for (int e = 0; e < 192; e += 4) {
      a0 += wp_[(size_t)(e + 0) * E] * xh[e + 0];
      a1 += wp_[(size_t)(e + 1) * E] * xh[e + 1];
      a2 += wp_[(size_t)(e + 2) * E] * xh[e + 2];
      a3 += wp_[(size_t)(e + 3) * E] * xh[e + 3];
    }
    ps[tid] = (a0 + a1) + (a2 + a3);
  }
  __syncthreads();
  if (tid < 384) om[tid] = ps[tid] + ps[384 + tid] + bo[tid];
  __syncthreads();

  {  // stage 3: out[o] = Wp[o,:]·om + bp   (3-way K-split of 384)
    const int o = tid % 256, ks = tid / 256;
    const float* xh = om + ks * 128;
    const float* wp_ = wpt + (size_t)(ks * 128) * OUTD + o;
    float a0 = 0.f, a1 = 0.f, a2 = 0.f, a3 = 0.f;
#pragma unroll 4
    for (int e = 0; e < 128; e += 4) {
      a0 += wp_[(size_t)(e + 0) * OUTD] * xh[e + 0];
      a1 += wp_[(size_t)(e + 1) * OUTD] * xh[e + 1];
      a2 += wp_[(size_t)(e + 2) * OUTD] * xh[e + 2];
      a3 += wp_[(size_t)(e + 3) * OUTD] * xh[e + 3];
    }
    ps[tid] = (a0 + a1) + (a2 + a3);
  }
  __syncthreads();
  if (tid < 256)
    out[(size_t)g * OUTD + tid] = ps[tid] + ps[256 + tid] + ps[512 + tid] + bp[tid];
}

// ---------------------------------------------------------------------------
extern "C" void kernel_launch(void* const* d_in, const int* in_sizes, int n_in,
                              void* d_out, int out_size, void* d_ws, size_t ws_size,
                              hipStream_t stream) {
  const float* x     = (const float*)d_in[0];
  const int*   sizes = (const int*)d_in[1];
  const float* query = (const float*)d_in[2];
  const float* Wq    = (const float*)d_in[3];
  const float* bq    = (const float*)d_in[4];
  const float* Wk    = (const float*)d_in[5];
  const float* bk    = (const float*)d_in[6];
  const float* Wv    = (const float*)d_in[7];
  const float* bv    = (const float*)d_in[8];
  const float* Wo    = (const float*)d_in[9];
  const float* bo    = (const float*)d_in[10];
  const float* Wp    = (const float*)d_in[11];
  const float* bp    = (const float*)d_in[12];
  float* wsf = (float*)d_ws;
  float* out = (float*)d_out;

  hipLaunchKernelGGL(k0a_scan_qv, dim3(97), dim3(256), 0, stream,
                     sizes, query, Wq, bq, wsf);
  hipLaunchKernelGGL(k0b_qk, dim3(36), dim3(256), 0, stream, Wk, bk, wsf);
  hipLaunchKernelGGL(k0t_transpose, dim3(96), dim3(256), 0, stream,
                     Wv, Wo, Wp, wsf);
  hipLaunchKernelGGL(k12_fused, dim3(G * SLOTS), dim3(384), 0, stream,
                     x, sizes, wsf);
  hipLaunchKernelGGL(k3_group, dim3(G), dim3(768), 0, stream,
                     wsf, sizes, bv, bo, bp, out);
}

// Round 7
// 375.158 us; speedup vs baseline: 1.0667x; 1.0667x over previous
//
#include <hip/hip_runtime.h>
#include <math.h>

// Problem constants (fixed-shape problem)
#define NN 131072   // nodes
#define G  256      // groups
#define E  384      // embed
#define H  6        // heads
#define DH 64       // head dim
#define OUTD 256    // output dim
#define MAXN 1024   // max segment length

#define CHK 32      // nodes per chunk (one wave per chunk)
#define SLOTS 32    // max chunks per group (ceil(MAXN/CHK))
#define PART_STRIDE 2316   // 6*384 acc + 6 m + 6 l

// Workspace layout (float indices)
#define WS_QK   0                       // 6*384 folded q@Wk
#define WS_C    2304                    // 6 folded q@bk
#define WS_OFF  2432                    // 256 int32 segment offsets
#define WS_QV   2944                    // 384 projected+scaled query
#define WS_WL   3328                    // 8192 int32 worklist (g<<5|s)
#define WS_M    11520                   // 1 int32 worklist count
#define WS_CS   11776                   // 256 int32 exclusive chunk-count scan
#define WS_PART 12288                   // 8192 slots x 2316 partials
#define WS_WVT  (WS_PART + G*SLOTS*PART_STRIDE)  // 384x384 Wv^T [e][i]
#define WS_WOT  (WS_WVT + E*E)          // 384x384 Wo^T [e][i]
#define WS_WPT  (WS_WOT + E*E)          // 384x256 Wp^T [e][o]

// ---------------------------------------------------------------------------
// K0a: block 0: offset scan + chunk-count scan + compacted worklist.
// blocks 1..96: qv rows.  qv = 0.125*(query@Wq.T + bq)
// ---------------------------------------------------------------------------
__global__ __launch_bounds__(256) void k0a_scan_qv(
    const int* __restrict__ sizes, const float* __restrict__ query,
    const float* __restrict__ Wq, const float* __restrict__ bq,
    float* __restrict__ wsf) {
  const int tid = threadIdx.x;
  if (blockIdx.x == 0) {
    __shared__ int s_scan[G];
    __shared__ int s_scan2[G];
    const int sz = sizes[tid];
    s_scan[tid] = sz;
    const int nch = (sz + CHK - 1) >> 5;           // 1..32
    s_scan2[tid] = nch;
    __syncthreads();
    for (int d = 1; d < G; d <<= 1) {
      int t = (tid >= d) ? s_scan[tid - d] : 0;
      int t2 = (tid >= d) ? s_scan2[tid - d] : 0;
      __syncthreads();
      s_scan[tid] += t;
      s_scan2[tid] += t2;
      __syncthreads();
    }
    ((int*)(wsf + WS_OFF))[tid] = s_scan[tid] - sz;    // exclusive node offset
    const int pos = s_scan2[tid] - nch;
    ((int*)(wsf + WS_CS))[tid] = pos;                  // exclusive chunk scan
    int* wl = (int*)(wsf + WS_WL);
    for (int s = 0; s < nch; s++) wl[pos + s] = (tid << 5) | s;
    if (tid == G - 1) ((int*)(wsf + WS_M))[0] = s_scan2[G - 1];
  } else {
    const int lane = tid & 63;
    const int i = (blockIdx.x - 1) * 4 + (tid >> 6);   // 0..383
    float a = 0.f;
#pragma unroll
    for (int j = 0; j < 6; j++)
      a += Wq[(size_t)i * E + j * 64 + lane] * query[j * 64 + lane];
#pragma unroll
    for (int mm = 1; mm < 64; mm <<= 1) a += __shfl_xor(a, mm, 64);
    if (lane == 0) wsf[WS_QV + i] = 0.125f * (a + bq[i]);
  }
}

// ---------------------------------------------------------------------------
// K0b: qk[h][e] = sum_d qv[h*64+d]*Wk[h*64+d][e].  36 blocks = (h, e-chunk64).
// ---------------------------------------------------------------------------
__global__ __launch_bounds__(256) void k0b_qk(
    const float* __restrict__ Wk, const float* __restrict__ bk,
    float* __restrict__ wsf) {
  __shared__ float qv_s[64];
  __shared__ float ps[256];
  const int h = blockIdx.x / 6, ec = blockIdx.x % 6;
  const int tid = threadIdx.x;
  if (tid < 64) qv_s[tid] = wsf[WS_QV + h * 64 + tid];
  __syncthreads();
  const int el = tid & 63, dq = tid >> 6;
  float a = 0.f;
#pragma unroll 4
  for (int d = dq * 16; d < dq * 16 + 16; d++)
    a += qv_s[d] * Wk[(size_t)(h * 64 + d) * E + ec * 64 + el];
  ps[tid] = a;
  __syncthreads();
  if (tid < 64)
    wsf[WS_QK + h * E + ec * 64 + tid] =
        ps[tid] + ps[64 + tid] + ps[128 + tid] + ps[192 + tid];
  if (ec == 0 && tid < 64) {                       // wave 0: c[h]
    float p = qv_s[tid] * bk[h * 64 + tid];
#pragma unroll
    for (int mm = 1; mm < 64; mm <<= 1) p += __shfl_xor(p, mm, 64);
    if (tid == 0) wsf[WS_C + h] = p;
  }
}

// ---------------------------------------------------------------------------
// K0t: transpose Wv, Wo (384x384) and Wp (256x384) into ws, 64x64 LDS tiles.
// ---------------------------------------------------------------------------
__global__ __launch_bounds__(256) void k0t_transpose(
    const float* __restrict__ Wv, const float* __restrict__ Wo,
    const float* __restrict__ Wp, float* __restrict__ wsf) {
  __shared__ float s[64][65];
  const int b = blockIdx.x;
  const float* src;
  float* dst;
  int R, tr, tc;
  if (b < 36)      { src = Wv; dst = wsf + WS_WVT; R = 384; tr = b / 6;        tc = b % 6; }
  else if (b < 72) { src = Wo; dst = wsf + WS_WOT; R = 384; tr = (b - 36) / 6; tc = (b - 36) % 6; }
  else             { src = Wp; dst = wsf + WS_WPT; R = 256; tr = (b - 72) / 6; tc = (b - 72) % 6; }
  const int r0 = tr * 64, c0 = tc * 64;
#pragma unroll
  for (int k = 0; k < 16; k++) {
    int idx = k * 256 + threadIdx.x;
    int r = idx >> 6, cc = idx & 63;
    s[r][cc] = src[(size_t)(r0 + r) * E + c0 + cc];
  }
  __syncthreads();
#pragma unroll
  for (int k = 0; k < 16; k++) {
    int idx = k * 256 + threadIdx.x;
    int cc = idx >> 6, r = idx & 63;
    dst[(size_t)(c0 + cc) * R + r0 + r] = s[r][cc];
  }
}

// ---------------------------------------------------------------------------
// K12 v4: wave-autonomous.  One WAVE = one 32-node chunk; no __syncthreads
// after init, no inter-wave coupling.  Per wave: scores (8 lanes/node, R5's
// conflict-free layout, 16-load batches) -> softmax in lanes 0..31 (node =
// lane, width-32 shuffles) -> pool re-read of the same rows (L2/L3-hot,
// f4-column per lane) -> partial (acc,m,l) store.  4352 waves ~= M alive.
// ---------------------------------------------------------------------------
__global__ __launch_bounds__(256) void k12_fused(
    const float* __restrict__ x, const int* __restrict__ sizes,
    float* __restrict__ wsf) {
  __shared__ float qk_l[8 * 292];      // 9.3 KB, broadcast-read
  __shared__ float c_s[8];
  __shared__ float pe2[4][CHK * 8];    // 4 KB: per-wave prob slab [n][8]
  const int tid = threadIdx.x;
  for (int idx = tid; idx < 2304; idx += 256) {    // k1-proven layout
    int sub = idx / 288, r3 = idx % 288;
    int h = r3 / 48, r2 = r3 % 48, j = r2 >> 2, r = r2 & 3;
    qk_l[sub * 292 + h * 48 + j * 4 + r] =
        wsf[WS_QK + h * E + (j * 8 + sub) * 4 + r];
  }
  if (tid < 8) c_s[tid] = (tid < 6) ? wsf[WS_C + tid] : 0.f;
  __syncthreads();                                 // only barrier in kernel

  const int lane = tid & 63, w = tid >> 6;
  const int gw = blockIdx.x * 4 + w;               // global wave id
  const int M = ((const int*)(wsf + WS_M))[0];
  if (gw >= M) return;                             // wave-uniform exit
  const int item = ((const int*)(wsf + WS_WL))[gw];
  const int g = item >> 5, s = item & 31;
  const int Ng = sizes[g];
  const int rem = Ng - s * CHK;
  const int clen = rem < CHK ? rem : CHK;
  const int n0 = ((const int*)(wsf + WS_OFF))[g] + s * CHK;
  float* pe = pe2[w];
  float* pslot = wsf + WS_PART + (size_t)gw * PART_STRIDE;
  const int sub = lane & 7, nod = lane >> 3;
  const float4* x4 = (const float4*)x;

  {  // phase A: scores for the 32 nodes (o=0..3 x nod), 8 lanes per node
    float acc[4][6];
#pragma unroll
    for (int o = 0; o < 4; o++)
#pragma unroll
      for (int h = 0; h < 6; h++) acc[o][h] = 0.f;
#pragma unroll 4
    for (int j = 0; j < 12; j++) {
      float4 qk4[6];
#pragma unroll
      for (int h = 0; h < 6; h++)
        qk4[h] = *(const float4*)&qk_l[sub * 292 + h * 48 + j * 4];
      float4 xv[4];
#pragma unroll
      for (int o = 0; o < 4; o++) {
        int nn = o * 8 + nod;
        nn = nn < clen ? nn : clen - 1;
        xv[o] = x4[(size_t)(n0 + nn) * 96 + j * 8 + sub];
      }
#pragma unroll
      for (int o = 0; o < 4; o++)
#pragma unroll
        for (int h = 0; h < 6; h++)
          acc[o][h] += qk4[h].x * xv[o].x + qk4[h].y * xv[o].y
                     + qk4[h].z * xv[o].z + qk4[h].w * xv[o].w;
    }
#pragma unroll
    for (int o = 0; o < 4; o++) {
#pragma unroll
      for (int h = 0; h < 6; h++) {
        acc[o][h] += __shfl_xor(acc[o][h], 1, 64);
        acc[o][h] += __shfl_xor(acc[o][h], 2, 64);
        acc[o][h] += __shfl_xor(acc[o][h], 4, 64);
      }
      float v = acc[o][0];
#pragma unroll
      for (int h = 1; h < 6; h++) v = (sub == h) ? acc[o][h] : v;
      const int nl = o * 8 + nod;
      if (sub < 6)
        pe[nl * 8 + sub] = (nl < clen) ? v + c_s[sub] : -1.0e30f;
    }
  }

  if (lane < 32) {  // phase B: softmax, node = lane, width-32 shuffles
    const float4 sA = *(const float4*)&pe[lane * 8];
    const float2 sB = *(const float2*)&pe[lane * 8 + 4];
    float sc[6] = {sA.x, sA.y, sA.z, sA.w, sB.x, sB.y};
    float mh[6], lh[6], eh[6];
#pragma unroll
    for (int h = 0; h < 6; h++) {
      float t = sc[h];
#pragma unroll
      for (int mm = 1; mm < 32; mm <<= 1) t = fmaxf(t, __shfl_xor(t, mm, 32));
      mh[h] = t;
      eh[h] = __expf(sc[h] - t);
    }
#pragma unroll
    for (int h = 0; h < 6; h++) {
      float t = eh[h];
#pragma unroll
      for (int mm = 1; mm < 32; mm <<= 1) t += __shfl_xor(t, mm, 32);
      lh[h] = t;
    }
    *(float4*)&pe[lane * 8] = make_float4(eh[0], eh[1], eh[2], eh[3]);
    *(float2*)&pe[lane * 8 + 4] = make_float2(eh[4], eh[5]);
    if (lane < 6) {
      float vm = mh[0], vl = lh[0];
#pragma unroll
      for (int h = 1; h < 6; h++) {
        vm = (lane == h) ? mh[h] : vm;
        vl = (lane == h) ? lh[h] : vl;
      }
      pslot[2304 + lane] = vm;
      pslot[2310 + lane] = vl;
    }
  }

  {  // phase C: pool.  lane owns f4-cols {lane, 64+(lane&31)}; rows cache-hot
    float accA[6][4], accB[6][4];
#pragma unroll
    for (int h = 0; h < 6; h++)
#pragma unroll
      for (int c = 0; c < 4; c++) { accA[h][c] = 0.f; accB[h][c] = 0.f; }
    const float4* xr = x4 + (size_t)n0 * 96;
    const int colB = 64 + (lane & 31);
#pragma unroll 2
    for (int n = 0; n < clen; n++) {
      const float4 xA = xr[n * 96 + lane];
      const float4 xB = xr[n * 96 + colB];
      const float4 pA = *(const float4*)&pe[n * 8];
      const float2 pB = *(const float2*)&pe[n * 8 + 4];
      const float ph[6] = {pA.x, pA.y, pA.z, pA.w, pB.x, pB.y};
#pragma unroll
      for (int h = 0; h < 6; h++) {
        accA[h][0] += ph[h] * xA.x; accA[h][1] += ph[h] * xA.y;
        accA[h][2] += ph[h] * xA.z; accA[h][3] += ph[h] * xA.w;
        accB[h][0] += ph[h] * xB.x; accB[h][1] += ph[h] * xB.y;
        accB[h][2] += ph[h] * xB.z; accB[h][3] += ph[h] * xB.w;
      }
    }
#pragma unroll
    for (int h = 0; h < 6; h++)
      *(float4*)&pslot[h * E + lane * 4] =
          make_float4(accA[h][0], accA[h][1], accA[h][2], accA[h][3]);
    if (lane < 32)
#pragma unroll
      for (int h = 0; h < 6; h++)
        *(float4*)&pslot[h * E + 256 + lane * 4] =
            make_float4(accB[h][0], accB[h][1], accB[h][2], accB[h][3]);
  }
}

// ---------------------------------------------------------------------------
// K3: one block (768 thr) per group.  Flash-combine <=32 chunk partials
// (m/l staged to LDS in parallel) -> xb; then thread-per-output chain on
// transposed weights (coalesced, L2-resident), K-split, combine via LDS.
// ---------------------------------------------------------------------------
__global__ __launch_bounds__(768) void k3_group(
    const float* __restrict__ wsf, const int* __restrict__ sizes,
    const float* __restrict__ bv, const float* __restrict__ bo,
    const float* __restrict__ bp, float* __restrict__ out) {
  __shared__ float xb[H * E];          // 9.2 KB
  __shared__ float pooled[E];
  __shared__ float om[E];
  __shared__ float ps[768];
  __shared__ float msh[SLOTS][H], lsh[SLOTS][H], wgt[SLOTS][H];
  __shared__ float linv[H];
  const int tid = threadIdx.x;
  const int g = blockIdx.x;
  const int nch = (sizes[g] + CHK - 1) >> 5;       // 1..32
  const int base_s = ((const int*)(wsf + WS_CS))[g];
  const float* pg = wsf + WS_PART + (size_t)base_s * PART_STRIDE;
  const float* wvt = wsf + WS_WVT;
  const float* wot = wsf + WS_WOT;
  const float* wpt = wsf + WS_WPT;

  if (tid < SLOTS * H) {
    const int s2 = tid / H, h2 = tid % H;
    if (s2 < nch) {
      msh[s2][h2] = pg[(size_t)s2 * PART_STRIDE + 2304 + h2];
      lsh[s2][h2] = pg[(size_t)s2 * PART_STRIDE + 2310 + h2];
    }
  }
  __syncthreads();
  if (tid < H) {
    float m = -3.0e38f;
    for (int s = 0; s < nch; s++) m = fmaxf(m, msh[s][tid]);
    float L = 0.f;
    for (int s = 0; s < nch; s++) {
      float wv_ = __expf(msh[s][tid] - m);
      wgt[s][tid] = wv_;
      L += lsh[s][tid] * wv_;
    }
    linv[tid] = 1.f / L;
  }
  __syncthreads();
  for (int idx = tid; idx < H * E; idx += 768) {
    int h = idx / E;
    float a = 0.f;
    for (int s = 0; s < nch; s++) a += pg[(size_t)s * PART_STRIDE + idx] * wgt[s][h];
    xb[idx] = a * linv[h];
  }
  __syncthreads();

  {  // stage 1: pooled[i] = Wv[i,:]·xb[head(i),:] + bv
    const int i = tid % 384, ks = tid / 384;
    const float* xh = xb + (i >> 6) * E + ks * 192;
    const float* wp_ = wvt + (size_t)(ks * 192) * E + i;
    float a0 = 0.f, a1 = 0.f, a2 = 0.f, a3 = 0.f;
#pragma unroll 4
    for (int e = 0; e < 192; e += 4) {
      a0 += wp_[(size_t)(e + 0) * E] * xh[e + 0];
      a1 += wp_[(size_t)(e + 1) * E] * xh[e + 1];
      a2 += wp_[(size_t)(e + 2) * E] * xh[e + 2];
      a3 += wp_[(size_t)(e + 3) * E] * xh[e + 3];
    }
    ps[tid] = (a0 + a1) + (a2 + a3);
  }
  __syncthreads();
  if (tid < 384) pooled[tid] = ps[tid] + ps[384 + tid] + bv[tid];
  __syncthreads();

  {  // stage 2: om[i] = Wo[i,:]·pooled + bo
    const int i = tid % 384, ks = tid / 384;
    const float* xh = pooled + ks * 192;
    const float* wp_ = wot + (size_t)(ks * 192) * E + i;
    float a0 = 0.f, a1 = 0.f, a2 = 0.f, a3 = 0.f;
#pragma unroll 4
    for (int e = 0; e < 192; e += 4) {
      a0 += wp_[(size_t)(e + 0) * E] * xh[e + 0];
      a1 += wp_[(size_t)(e + 1) * E] * xh[e + 1];
      a2 += wp_[(size_t)(e + 2) * E] * xh[e + 2];
      a3 += wp_[(size_t)(e + 3) * E] * xh[e + 3];
    }
    ps[tid] = (a0 + a1) + (a2 + a3);
  }
  __syncthreads();
  if (tid < 384) om[tid] = ps[tid] + ps[384 + tid] + bo[tid];
  __syncthreads();

  {  // stage 3: out[o] = Wp[o,:]·om + bp   (3-way K-split of 384)
    const int o = tid % 256, ks = tid / 256;
    const float* xh = om + ks * 128;
    const float* wp_ = wpt + (size_t)(ks * 128) * OUTD + o;
    float a0 = 0.f, a1 = 0.f, a2 = 0.f, a3 = 0.f;
#pragma unroll 4
    for (int e = 0; e < 128; e += 4) {
      a0 += wp_[(size_t)(e + 0) * OUTD] * xh[e + 0];
      a1 += wp_[(size_t)(e + 1) * OUTD] * xh[e + 1];
      a2 += wp_[(size_t)(e + 2) * OUTD] * xh[e + 2];
      a3 += wp_[(size_t)(e + 3) * OUTD] * xh[e + 3];
    }
    ps[tid] = (a0 + a1) + (a2 + a3);
  }
  __syncthreads();
  if (tid < 256)
    out[(size_t)g * OUTD + tid] = ps[tid] + ps[256 + tid] + ps[512 + tid] + bp[tid];
}

// ---------------------------------------------------------------------------
extern "C" void kernel_launch(void* const* d_in, const int* in_sizes, int n_in,
                              void* d_out, int out_size, void* d_ws, size_t ws_size,
                              hipStream_t stream) {
  const float* x     = (const float*)d_in[0];
  const int*   sizes = (const int*)d_in[1];
  const float* query = (const float*)d_in[2];
  const float* Wq    = (const float*)d_in[3];
  const float* bq    = (const float*)d_in[4];
  const float* Wk    = (const float*)d_in[5];
  const float* bk    = (const float*)d_in[6];
  const float* Wv    = (const float*)d_in[7];
  const float* bv    = (const float*)d_in[8];
  const float* Wo    = (const float*)d_in[9];
  const float* bo    = (const float*)d_in[10];
  const float* Wp    = (const float*)d_in[11];
  const float* bp    = (const float*)d_in[12];
  float* wsf = (float*)d_ws;
  float* out = (float*)d_out;

  hipLaunchKernelGGL(k0a_scan_qv, dim3(97), dim3(256), 0, stream,
                     sizes, query, Wq, bq, wsf);
  hipLaunchKernelGGL(k0b_qk, dim3(36), dim3(256), 0, stream, Wk, bk, wsf);
  hipLaunchKernelGGL(k0t_transpose, dim3(96), dim3(256), 0, stream,
                     Wv, Wo, Wp, wsf);
  // 1088 blocks x 4 waves = 4352 waves >= M (max 4352 chunks), wave-per-chunk
  hipLaunchKernelGGL(k12_fused, dim3(1088), dim3(256), 0, stream,
                     x, sizes, wsf);
  hipLaunchKernelGGL(k3_group, dim3(G), dim3(768), 0, stream,
                     wsf, sizes, bv, bo, bp, out);
}

// Round 8
// 366.744 us; speedup vs baseline: 1.0912x; 1.0229x over previous
//
#include <hip/hip_runtime.h>
#include <math.h>

// Problem constants (fixed-shape problem)
#define NN 131072   // nodes
#define G  256      // groups
#define E  384      // embed
#define H  6        // heads
#define DH 64       // head dim
#define OUTD 256    // output dim
#define MAXN 1024   // max segment length

#define CHK 32      // nodes per chunk (one 2-wave block per chunk)
#define SLOTS 32    // max chunks per group (ceil(MAXN/CHK))
#define PART_STRIDE 2316   // 6*384 acc + 6 m + 6 l

// Workspace layout (float indices)
#define WS_QK   0                       // 6*384 folded q@Wk
#define WS_C    2304                    // 6 folded q@bk
#define WS_OFF  2432                    // 256 int32 segment offsets
#define WS_QV   2944                    // 384 projected+scaled query
#define WS_WL   3328                    // 8192 int32 worklist (g<<5|s)
#define WS_M    11520                   // 1 int32 worklist count
#define WS_CS   11776                   // 256 int32 exclusive chunk-count scan
#define WS_PART 12288                   // 8192 slots x 2316 partials
#define WS_WVT  (WS_PART + G*SLOTS*PART_STRIDE)  // 384x384 Wv^T [e][i]
#define WS_WOT  (WS_WVT + E*E)          // 384x384 Wo^T [e][i]
#define WS_WPT  (WS_WOT + E*E)          // 384x256 Wp^T [e][o]

// ---------------------------------------------------------------------------
// K0a: block 0: offset scan + chunk-count scan + compacted worklist.
// blocks 1..96: qv rows.  qv = 0.125*(query@Wq.T + bq)
// ---------------------------------------------------------------------------
__global__ __launch_bounds__(256) void k0a_scan_qv(
    const int* __restrict__ sizes, const float* __restrict__ query,
    const float* __restrict__ Wq, const float* __restrict__ bq,
    float* __restrict__ wsf) {
  const int tid = threadIdx.x;
  if (blockIdx.x == 0) {
    __shared__ int s_scan[G];
    __shared__ int s_scan2[G];
    const int sz = sizes[tid];
    s_scan[tid] = sz;
    const int nch = (sz + CHK - 1) >> 5;           // 1..32
    s_scan2[tid] = nch;
    __syncthreads();
    for (int d = 1; d < G; d <<= 1) {
      int t = (tid >= d) ? s_scan[tid - d] : 0;
      int t2 = (tid >= d) ? s_scan2[tid - d] : 0;
      __syncthreads();
      s_scan[tid] += t;
      s_scan2[tid] += t2;
      __syncthreads();
    }
    ((int*)(wsf + WS_OFF))[tid] = s_scan[tid] - sz;    // exclusive node offset
    const int pos = s_scan2[tid] - nch;
    ((int*)(wsf + WS_CS))[tid] = pos;                  // exclusive chunk scan
    int* wl = (int*)(wsf + WS_WL);
    for (int s = 0; s < nch; s++) wl[pos + s] = (tid << 5) | s;
    if (tid == G - 1) ((int*)(wsf + WS_M))[0] = s_scan2[G - 1];
  } else {
    const int lane = tid & 63;
    const int i = (blockIdx.x - 1) * 4 + (tid >> 6);   // 0..383
    float a = 0.f;
#pragma unroll
    for (int j = 0; j < 6; j++)
      a += Wq[(size_t)i * E + j * 64 + lane] * query[j * 64 + lane];
#pragma unroll
    for (int mm = 1; mm < 64; mm <<= 1) a += __shfl_xor(a, mm, 64);
    if (lane == 0) wsf[WS_QV + i] = 0.125f * (a + bq[i]);
  }
}

// ---------------------------------------------------------------------------
// K0b: qk[h][e] = sum_d qv[h*64+d]*Wk[h*64+d][e].  36 blocks = (h, e-chunk64).
// ---------------------------------------------------------------------------
__global__ __launch_bounds__(256) void k0b_qk(
    const float* __restrict__ Wk, const float* __restrict__ bk,
    float* __restrict__ wsf) {
  __shared__ float qv_s[64];
  __shared__ float ps[256];
  const int h = blockIdx.x / 6, ec = blockIdx.x % 6;
  const int tid = threadIdx.x;
  if (tid < 64) qv_s[tid] = wsf[WS_QV + h * 64 + tid];
  __syncthreads();
  const int el = tid & 63, dq = tid >> 6;
  float a = 0.f;
#pragma unroll 4
  for (int d = dq * 16; d < dq * 16 + 16; d++)
    a += qv_s[d] * Wk[(size_t)(h * 64 + d) * E + ec * 64 + el];
  ps[tid] = a;
  __syncthreads();
  if (tid < 64)
    wsf[WS_QK + h * E + ec * 64 + tid] =
        ps[tid] + ps[64 + tid] + ps[128 + tid] + ps[192 + tid];
  if (ec == 0 && tid < 64) {                       // wave 0: c[h]
    float p = qv_s[tid] * bk[h * 64 + tid];
#pragma unroll
    for (int mm = 1; mm < 64; mm <<= 1) p += __shfl_xor(p, mm, 64);
    if (tid == 0) wsf[WS_C + h] = p;
  }
}

// ---------------------------------------------------------------------------
// K0t: transpose Wv, Wo (384x384) and Wp (256x384) into ws, 64x64 LDS tiles.
// ---------------------------------------------------------------------------
__global__ __launch_bounds__(256) void k0t_transpose(
    const float* __restrict__ Wv, const float* __restrict__ Wo,
    const float* __restrict__ Wp, float* __restrict__ wsf) {
  __shared__ float s[64][65];
  const int b = blockIdx.x;
  const float* src;
  float* dst;
  int R, tr, tc;
  if (b < 36)      { src = Wv; dst = wsf + WS_WVT; R = 384; tr = b / 6;        tc = b % 6; }
  else if (b < 72) { src = Wo; dst = wsf + WS_WOT; R = 384; tr = (b - 36) / 6; tc = (b - 36) % 6; }
  else             { src = Wp; dst = wsf + WS_WPT; R = 256; tr = (b - 72) / 6; tc = (b - 72) % 6; }
  const int r0 = tr * 64, c0 = tc * 64;
#pragma unroll
  for (int k = 0; k < 16; k++) {
    int idx = k * 256 + threadIdx.x;
    int r = idx >> 6, cc = idx & 63;
    s[r][cc] = src[(size_t)(r0 + r) * E + c0 + cc];
  }
  __syncthreads();
#pragma unroll
  for (int k = 0; k < 16; k++) {
    int idx = k * 256 + threadIdx.x;
    int cc = idx >> 6, r = idx & 63;
    dst[(size_t)(c0 + cc) * R + r0 + r] = s[r][cc];
  }
}

// ---------------------------------------------------------------------------
// K12 v5: one 2-WAVE block (128 thr) per 32-node chunk -> ~8448 waves
// (33/CU launched vs 16.5 before): doubles resident load-issuers, which is
// the measured bottleneck (waves average ~0.3 outstanding loads at 1.85TB/s).
// wave0: scores nodes 0-15, softmax, pool cols 0-255.
// wave1: scores nodes 16-31, pool cols 256-383 (2 nodes/load, xor-32 merge).
// Cheap 2-wave __syncthreads between phases.
// ---------------------------------------------------------------------------
__global__ __launch_bounds__(128, 6) void k12_fused(
    const float* __restrict__ x, const int* __restrict__ sizes,
    float* __restrict__ wsf) {
  __shared__ float qk_l[8 * 292];      // 9.3 KB, broadcast-read
  __shared__ float c_s[8];
  __shared__ float pe[CHK * 8];        // 1 KB: probs [n][8]
  const int M = ((const int*)(wsf + WS_M))[0];
  if ((int)blockIdx.x >= M) return;    // dead block, exits immediately
  const int item = ((const int*)(wsf + WS_WL))[blockIdx.x];
  const int g = item >> 5, s = item & 31;
  const int Ng = sizes[g];
  const int rem = Ng - s * CHK;
  const int clen = rem < CHK ? rem : CHK;
  const int n0 = ((const int*)(wsf + WS_OFF))[g] + s * CHK;
  const int tid = threadIdx.x;
  const int lane = tid & 63, w = tid >> 6;         // 2 waves

  for (int idx = tid; idx < 2304; idx += 128) {    // qk: k1-proven layout
    int sub = idx / 288, r3 = idx % 288;
    int h = r3 / 48, r2 = r3 % 48, j = r2 >> 2, r = r2 & 3;
    qk_l[sub * 292 + h * 48 + j * 4 + r] =
        wsf[WS_QK + h * E + (j * 8 + sub) * 4 + r];
  }
  if (tid < 8) c_s[tid] = (tid < 6) ? wsf[WS_C + tid] : 0.f;
  __syncthreads();

  const int sub = lane & 7, nod = lane >> 3;
  const float4* x4 = (const float4*)x;
  float* pslot = wsf + WS_PART + (size_t)blockIdx.x * PART_STRIDE;

  {  // phase A: wave w -> nodes w*16 .. w*16+15 (2 o-slots), 8 lanes/node
    float acc[2][6];
#pragma unroll
    for (int o = 0; o < 2; o++)
#pragma unroll
      for (int h = 0; h < 6; h++) acc[o][h] = 0.f;
#pragma unroll 4
    for (int j = 0; j < 12; j++) {
      float4 qk4[6];
#pragma unroll
      for (int h = 0; h < 6; h++)
        qk4[h] = *(const float4*)&qk_l[sub * 292 + h * 48 + j * 4];
      float4 xv[2];
#pragma unroll
      for (int o = 0; o < 2; o++) {
        int nn = w * 16 + o * 8 + nod;
        nn = nn < clen ? nn : clen - 1;
        xv[o] = x4[(size_t)(n0 + nn) * 96 + j * 8 + sub];
      }
#pragma unroll
      for (int o = 0; o < 2; o++)
#pragma unroll
        for (int h = 0; h < 6; h++)
          acc[o][h] += qk4[h].x * xv[o].x + qk4[h].y * xv[o].y
                     + qk4[h].z * xv[o].z + qk4[h].w * xv[o].w;
    }
#pragma unroll
    for (int o = 0; o < 2; o++) {
#pragma unroll
      for (int h = 0; h < 6; h++) {
        acc[o][h] += __shfl_xor(acc[o][h], 1, 64);
        acc[o][h] += __shfl_xor(acc[o][h], 2, 64);
        acc[o][h] += __shfl_xor(acc[o][h], 4, 64);
      }
      float v = acc[o][0];
#pragma unroll
      for (int h = 1; h < 6; h++) v = (sub == h) ? acc[o][h] : v;
      const int nl = w * 16 + o * 8 + nod;
      if (sub < 6)
        pe[nl * 8 + sub] = (nl < clen) ? v + c_s[sub] : -1.0e30f;
    }
  }
  __syncthreads();

  if (w == 0 && lane < 32) {  // phase B: softmax, node = lane, width-32
    const float4 sA = *(const float4*)&pe[lane * 8];
    const float2 sB = *(const float2*)&pe[lane * 8 + 4];
    float sc[6] = {sA.x, sA.y, sA.z, sA.w, sB.x, sB.y};
    float mh[6], lh[6], eh[6];
#pragma unroll
    for (int h = 0; h < 6; h++) {
      float t = sc[h];
#pragma unroll
      for (int mm = 1; mm < 32; mm <<= 1) t = fmaxf(t, __shfl_xor(t, mm, 32));
      mh[h] = t;
      eh[h] = __expf(sc[h] - t);
    }
#pragma unroll
    for (int h = 0; h < 6; h++) {
      float t = eh[h];
#pragma unroll
      for (int mm = 1; mm < 32; mm <<= 1) t += __shfl_xor(t, mm, 32);
      lh[h] = t;
    }
    *(float4*)&pe[lane * 8] = make_float4(eh[0], eh[1], eh[2], eh[3]);
    *(float2*)&pe[lane * 8 + 4] = make_float2(eh[4], eh[5]);
    if (lane < 6) {
      float vm = mh[0], vl = lh[0];
#pragma unroll
      for (int h = 1; h < 6; h++) {
        vm = (lane == h) ? mh[h] : vm;
        vl = (lane == h) ? lh[h] : vl;
      }
      pslot[2304 + lane] = vm;
      pslot[2310 + lane] = vl;
    }
  }
  __syncthreads();

  const float4* xr = x4 + (size_t)n0 * 96;
  if (w == 0) {  // phase C0: pool cols 0-255 (f4col = lane), all 32 nodes
    float acc[6][4];
#pragma unroll
    for (int h = 0; h < 6; h++)
#pragma unroll
      for (int c = 0; c < 4; c++) acc[h][c] = 0.f;
#pragma unroll 2
    for (int n = 0; n < clen; n++) {
      const float4 xA = xr[n * 96 + lane];
      const float4 pA = *(const float4*)&pe[n * 8];
      const float2 pB = *(const float2*)&pe[n * 8 + 4];
      const float ph[6] = {pA.x, pA.y, pA.z, pA.w, pB.x, pB.y};
#pragma unroll
      for (int h = 0; h < 6; h++) {
        acc[h][0] += ph[h] * xA.x; acc[h][1] += ph[h] * xA.y;
        acc[h][2] += ph[h] * xA.z; acc[h][3] += ph[h] * xA.w;
      }
    }
#pragma unroll
    for (int h = 0; h < 6; h++)
      *(float4*)&pslot[h * E + lane * 4] =
          make_float4(acc[h][0], acc[h][1], acc[h][2], acc[h][3]);
  } else {  // phase C1: cols 256-383; lane<32 even nodes, lane>=32 odd nodes
    float acc[6][4];
#pragma unroll
    for (int h = 0; h < 6; h++)
#pragma unroll
      for (int c = 0; c < 4; c++) acc[h][c] = 0.f;
    const int colB = 64 + (lane & 31);
    const int par = lane >> 5;                     // node parity
#pragma unroll 2
    for (int n = 0; n < CHK; n += 2) {
      const int nl = n + par;                      // padded node index
      int nn = nl < clen ? nl : clen - 1;          // clamped row (pad p = 0)
      const float4 xB = xr[nn * 96 + colB];
      const float4 pA = *(const float4*)&pe[nl * 8];
      const float2 pB = *(const float2*)&pe[nl * 8 + 4];
      const float ph[6] = {pA.x, pA.y, pA.z, pA.w, pB.x, pB.y};
#pragma unroll
      for (int h = 0; h < 6; h++) {
        acc[h][0] += ph[h] * xB.x; acc[h][1] += ph[h] * xB.y;
        acc[h][2] += ph[h] * xB.z; acc[h][3] += ph[h] * xB.w;
      }
    }
#pragma unroll
    for (int h = 0; h < 6; h++)
#pragma unroll
      for (int c = 0; c < 4; c++)
        acc[h][c] += __shfl_xor(acc[h][c], 32, 64);  // merge parities
    if (lane < 32)
#pragma unroll
      for (int h = 0; h < 6; h++)
        *(float4*)&pslot[h * E + 256 + lane * 4] =
            make_float4(acc[h][0], acc[h][1], acc[h][2], acc[h][3]);
  }
}

// ---------------------------------------------------------------------------
// K3: one block (768 thr) per group.  Flash-combine <=32 chunk partials
// (m/l staged to LDS in parallel) -> xb; then thread-per-output chain on
// transposed weights (coalesced, L2-resident), K-split, combine via LDS.
// ---------------------------------------------------------------------------
__global__ __launch_bounds__(768) void k3_group(
    const float* __restrict__ wsf, const int* __restrict__ sizes,
    const float* __restrict__ bv, const float* __restrict__ bo,
    const float* __restrict__ bp, float* __restrict__ out) {
  __shared__ float xb[H * E];          // 9.2 KB
  __shared__ float pooled[E];
  __shared__ float om[E];
  __shared__ float ps[768];
  __shared__ float msh[SLOTS][H], lsh[SLOTS][H], wgt[SLOTS][H];
  __shared__ float linv[H];
  const int tid = threadIdx.x;
  const int g = blockIdx.x;
  const int nch = (sizes[g] + CHK - 1) >> 5;       // 1..32
  const int base_s = ((const int*)(wsf + WS_CS))[g];
  const float* pg = wsf + WS_PART + (size_t)base_s * PART_STRIDE;
  const float* wvt = wsf + WS_WVT;
  const float* wot = wsf + WS_WOT;
  const float* wpt = wsf + WS_WPT;

  if (tid < SLOTS * H) {
    const int s2 = tid / H, h2 = tid % H;
    if (s2 < nch) {
      msh[s2][h2] = pg[(size_t)s2 * PART_STRIDE + 2304 + h2];
      lsh[s2][h2] = pg[(size_t)s2 * PART_STRIDE + 2310 + h2];
    }
  }
  __syncthreads();
  if (tid < H) {
    float m = -3.0e38f;
    for (int s = 0; s < nch; s++) m = fmaxf(m, msh[s][tid]);
    float L = 0.f;
    for (int s = 0; s < nch; s++) {
      float wv_ = __expf(msh[s][tid] - m);
      wgt[s][tid] = wv_;
      L += lsh[s][tid] * wv_;
    }
    linv[tid] = 1.f / L;
  }
  __syncthreads();
  for (int idx = tid; idx < H * E; idx += 768) {
    int h = idx / E;
    float a = 0.f;
    for (int s = 0; s < nch; s++) a += pg[(size_t)s * PART_STRIDE + idx] * wgt[s][h];
    xb[idx] = a * linv[h];
  }
  __syncthreads();

  {  // stage 1: pooled[i] = Wv[i,:]·xb[head(i),:] + bv
    const int i = tid % 384, ks = tid / 384;
    const float* xh = xb + (i >> 6) * E + ks * 192;
    const float* wp_ = wvt + (size_t)(ks * 192) * E + i;
    float a0 = 0.f, a1 = 0.f, a2 = 0.f, a3 = 0.f;
#pragma unroll 4
    for (int e = 0; e < 192; e += 4) {
      a0 += wp_[(size_t)(e + 0) * E] * xh[e + 0];
      a1 += wp_[(size_t)(e + 1) * E] * xh[e + 1];
      a2 += wp_[(size_t)(e + 2) * E] * xh[e + 2];
      a3 += wp_[(size_t)(e + 3) * E] * xh[e + 3];
    }
    ps[tid] = (a0 + a1) + (a2 + a3);
  }
  __syncthreads();
  if (tid < 384) pooled[tid] = ps[tid] + ps[384 + tid] + bv[tid];
  __syncthreads();

  {  // stage 2: om[i] = Wo[i,:]·pooled + bo
    const int i = tid % 384, ks = tid / 384;
    const float* xh = pooled + ks * 192;
    const float* wp_ = wot + (size_t)(ks * 192) * E + i;
    float a0 = 0.f, a1 = 0.f, a2 = 0.f, a3 = 0.f;
#pragma unroll 4
    for (int e = 0; e < 192; e += 4) {
      a0 += wp_[(size_t)(e + 0) * E] * xh[e + 0];
      a1 += wp_[(size_t)(e + 1) * E] * xh[e + 1];
      a2 += wp_[(size_t)(e + 2) * E] * xh[e + 2];
      a3 += wp_[(size_t)(e + 3) * E] * xh[e + 3];
    }
    ps[tid] = (a0 + a1) + (a2 + a3);
  }
  __syncthreads();
  if (tid < 384) om[tid] = ps[tid] + ps[384 + tid] + bo[tid];
  __syncthreads();

  {  // stage 3: out[o] = Wp[o,:]·om + bp   (3-way K-split of 384)
    const int o = tid % 256, ks = tid / 256;
    const float* xh = om + ks * 128;
    const float* wp_ = wpt + (size_t)(ks * 128) * OUTD + o;
    float a0 = 0.f, a1 = 0.f, a2 = 0.f, a3 = 0.f;
#pragma unroll 4
    for (int e = 0; e < 128; e += 4) {
      a0 += wp_[(size_t)(e + 0) * OUTD] * xh[e + 0];
      a1 += wp_[(size_t)(e + 1) * OUTD] * xh[e + 1];
      a2 += wp_[(size_t)(e + 2) * OUTD] * xh[e + 2];
      a3 += wp_[(size_t)(e + 3) * OUTD] * xh[e + 3];
    }
    ps[tid] = (a0 + a1) + (a2 + a3);
  }
  __syncthreads();
  if (tid < 256)
    out[(size_t)g * OUTD + tid] = ps[tid] + ps[256 + tid] + ps[512 + tid] + bp[tid];
}

// ---------------------------------------------------------------------------
extern "C" void kernel_launch(void* const* d_in, const int* in_sizes, int n_in,
                              void* d_out, int out_size, void* d_ws, size_t ws_size,
                              hipStream_t stream) {
  const float* x     = (const float*)d_in[0];
  const int*   sizes = (const int*)d_in[1];
  const float* query = (const float*)d_in[2];
  const float* Wq    = (const float*)d_in[3];
  const float* bq    = (const float*)d_in[4];
  const float* Wk    = (const float*)d_in[5];
  const float* bk    = (const float*)d_in[6];
  const float* Wv    = (const float*)d_in[7];
  const float* bv    = (const float*)d_in[8];
  const float* Wo    = (const float*)d_in[9];
  const float* bo    = (const float*)d_in[10];
  const float* Wp    = (const float*)d_in[11];
  const float* bp    = (const float*)d_in[12];
  float* wsf = (float*)d_ws;
  float* out = (float*)d_out;

  hipLaunchKernelGGL(k0a_scan_qv, dim3(97), dim3(256), 0, stream,
                     sizes, query, Wq, bq, wsf);
  hipLaunchKernelGGL(k0b_qk, dim3(36), dim3(256), 0, stream, Wk, bk, wsf);
  hipLaunchKernelGGL(k0t_transpose, dim3(96), dim3(256), 0, stream,
                     Wv, Wo, Wp, wsf);
  // 4352 blocks (>= max M) x 128 thr; one 2-wave block per 32-node chunk
  hipLaunchKernelGGL(k12_fused, dim3(4352), dim3(128), 0, stream,
                     x, sizes, wsf);
  hipLaunchKernelGGL(k3_group, dim3(G), dim3(768), 0, stream,
                     wsf, sizes, bv, bo, bp, out);
}